// Round 10
// baseline (110.457 us; speedup 1.0000x reference)
//
#include <hip/hip_runtime.h>
#include <stdint.h>

// B=128, T=256, C=384, H=6, D=64;  M = B*T = 32768
// GEMM1: xb[32768,384] x wt^T[1152,384] -> Q,K,V [B,H,T,D] (bf16)
//        256x128 tile, 512thr, BK=32, 3-buf counted-vmcnt pipeline (pinned),
//        XCD swizzle, T2 XOR-swizzled LDS
// attn : per (b,h), 8 waves x 32 q rows, swapped-QK^T flash, causal; Ot aliases Ks
// GEMM2: O[32768,384] x wpt[384,384] + bp -> out f32 (128x128, round-9 config)

typedef __attribute__((ext_vector_type(8))) short bf16x8;
typedef __attribute__((ext_vector_type(4))) float f32x4;
typedef __attribute__((ext_vector_type(16))) float f32x16;

__device__ __forceinline__ unsigned short f2b(float f) {
    union { float f; unsigned int u; } v; v.f = f;
    unsigned int u = v.u + 0x7fffu + ((v.u >> 16) & 1u);
    return (unsigned short)(u >> 16);
}

__device__ __forceinline__ unsigned int pk2(float lo, float hi) {
    return (unsigned int)f2b(lo) | ((unsigned int)f2b(hi) << 16);
}

__device__ __forceinline__ void gload_lds16(const void* g, void* lds) {
    auto gp = reinterpret_cast<const __attribute__((address_space(1))) uint32_t*>(
        reinterpret_cast<uintptr_t>(g));
    auto lp = reinterpret_cast<__attribute__((address_space(3))) uint32_t*>(
        reinterpret_cast<uintptr_t>(lds));
    __builtin_amdgcn_global_load_lds(gp, lp, 16, 0, 0);
}

#define SBAR0() __builtin_amdgcn_sched_barrier(0)

// ---------------- conversion kernels ----------------

__global__ void cvt_x_kernel(const float* __restrict__ x, unsigned short* __restrict__ xb, int n8) {
    int i = blockIdx.x * 256 + threadIdx.x;
    if (i >= n8) return;
    float4 a = ((const float4*)x)[(size_t)i * 2];
    float4 b = ((const float4*)x)[(size_t)i * 2 + 1];
    uint4 o;
    o.x = pk2(a.x, a.y); o.y = pk2(a.z, a.w);
    o.z = pk2(b.x, b.y); o.w = pk2(b.z, b.w);
    ((uint4*)xb)[i] = o;
}

// wt[j][c] = W_{p}[h][c][d]  (j = p*384 + h*64 + d), 1152x384
// wpt[n][c] = Wp[c][n], 384x384
__global__ void cvt_w_kernel(const float* __restrict__ Wq, const float* __restrict__ Wk,
                             const float* __restrict__ Wv, const float* __restrict__ Wp,
                             unsigned short* __restrict__ wt, unsigned short* __restrict__ wpt) {
    int i = blockIdx.x * 256 + threadIdx.x;
    if (i >= 589824) return;
    if (i < 442368) {
        int j = i / 384, c = i - j * 384;
        int p = j / 384, rem = j - p * 384;
        int h = rem >> 6, d = rem & 63;
        const float* W = (p == 0) ? Wq : ((p == 1) ? Wk : Wv);
        wt[i] = f2b(W[(size_t)(h * 384 + c) * 64 + d]);
    } else {
        int i2 = i - 442368;
        int n = i2 / 384, c = i2 - n * 384;
        wpt[i2] = f2b(Wp[(size_t)c * 384 + n]);
    }
}

// ---------------- GEMM1: qkv projections ----------------
// 256x128 tile, 512 threads = 8 waves (4M x 2N), BK=32, 3 LDS buffers, depth-2
// prefetch, counted vmcnt (3 loads/STAGE -> vmcnt(6)/(3)/(0)), pinned.
// T2 swizzle: LDS slot (row, o_l) holds global K-octet o_l ^ ((row>>1)&3).

__global__ __launch_bounds__(512, 4) void gemm_qkv(
    const unsigned short* __restrict__ xb,   // [32768][384]
    const unsigned short* __restrict__ wt,   // [1152][384]
    unsigned short* __restrict__ qO,         // [B][H][T][D]
    unsigned short* __restrict__ kO,         // [B][H][T][D]
    unsigned short* __restrict__ vO)         // [B][H][T][D]
{
    extern __shared__ __align__(16) unsigned short smem[];  // 73728 B
    unsigned short* AsBase = smem;            // [3][8192]  (256x32 each)
    unsigned short* BsBase = smem + 24576;    // [3][4096]  (128x32 each)

    const int tid  = threadIdx.x;
    const int lane = tid & 63;
    const int w    = tid >> 6;               // 0..7
    const int wm = w >> 1, wn = w & 1;       // 4M x 2N wave grid

    // XCD-aware swizzle: nwg = 1152 = 8*144
    const int flat = blockIdx.y * 9 + blockIdx.x;
    const int swz = (flat & 7) * 144 + (flat >> 3);
    const int bx = swz % 9, by = swz / 9;
    const int col0 = bx * 128;
    const int row0 = by * 256;

    const unsigned short* Abase = xb + (size_t)row0 * 384;
    const unsigned short* Bbase = wt + (size_t)col0 * 384;

    f32x4 acc[4][4];
#pragma unroll
    for (int mf = 0; mf < 4; ++mf)
#pragma unroll
        for (int nf = 0; nf < 4; ++nf)
#pragma unroll
            for (int r = 0; r < 4; ++r) acc[mf][nf][r] = 0.f;

    // A: 1024 chunks of 8 elems (256 rows x 4 octs); B: 512 chunks (128 rows x 4)
    // T2: row = ci>>2, global oct = (ci&3) ^ ((ci>>3)&3)   [XOR involution]
    const int ci0 = tid;
    const int ci1 = tid + 512;
    const unsigned short* aSrc0 = Abase + (size_t)(ci0 >> 2) * 384 + (((ci0 & 3) ^ ((ci0 >> 3) & 3))) * 8;
    const unsigned short* aSrc1 = Abase + (size_t)(ci1 >> 2) * 384 + (((ci1 & 3) ^ ((ci1 >> 3) & 3))) * 8;
    const unsigned short* bSrc0 = Bbase + (size_t)(ci0 >> 2) * 384 + (((ci0 & 3) ^ ((ci0 >> 3) & 3))) * 8;
    const int cb = w * 64;  // wave-uniform chunk base

    auto STAGE = [&](int buf, int kt) {
        const int k0_ = kt * 32;
        gload_lds16(aSrc0 + k0_, AsBase + buf * 8192 + (cb + 0) * 8);
        gload_lds16(aSrc1 + k0_, AsBase + buf * 8192 + (cb + 512) * 8);
        gload_lds16(bSrc0 + k0_, BsBase + buf * 4096 + (cb + 0) * 8);
    };

    const int fr = lane & 15;
    const int oc = (lane >> 4) ^ ((fr >> 1) & 3);   // frag bases are x16 -> row-invariant

    auto COMPUTE = [&](int buf) {
        const unsigned short* A = AsBase + buf * 8192;
        const unsigned short* B = BsBase + buf * 4096;
        bf16x8 aF[4], bF[4];
#pragma unroll
        for (int mf = 0; mf < 4; ++mf)
            aF[mf] = *(const bf16x8*)&A[(wm * 64 + mf * 16 + fr) * 32 + oc * 8];
#pragma unroll
        for (int nf = 0; nf < 4; ++nf)
            bF[nf] = *(const bf16x8*)&B[(wn * 64 + nf * 16 + fr) * 32 + oc * 8];
#pragma unroll
        for (int mf = 0; mf < 4; ++mf)
#pragma unroll
            for (int nf = 0; nf < 4; ++nf)
                acc[mf][nf] = __builtin_amdgcn_mfma_f32_16x16x32_bf16(aF[mf], bF[nf], acc[mf][nf], 0, 0, 0);
    };

    STAGE(0, 0);
    STAGE(1, 1);
    SBAR0();
    int bufS = 2, bufC = 0;
    for (int t = 0; t < 10; ++t) {
        STAGE(bufS, t + 2);
        bufS = (bufS == 2) ? 0 : bufS + 1;
        SBAR0();
        asm volatile("s_waitcnt vmcnt(6)" ::: "memory");
        SBAR0();
        __builtin_amdgcn_s_barrier();
        SBAR0();
        COMPUTE(bufC);
        bufC = (bufC == 2) ? 0 : bufC + 1;
        SBAR0();
        __builtin_amdgcn_s_barrier();
        SBAR0();
    }
    asm volatile("s_waitcnt vmcnt(3)" ::: "memory");
    SBAR0();
    __builtin_amdgcn_s_barrier();
    SBAR0();
    COMPUTE(1);
    SBAR0();
    __builtin_amdgcn_s_barrier();
    SBAR0();
    asm volatile("s_waitcnt vmcnt(0)" ::: "memory");
    SBAR0();
    __builtin_amdgcn_s_barrier();
    SBAR0();
    COMPUTE(2);
    __syncthreads();   // full drain before smem reuse as epilogue tile

    // ---- epilogue: 4 phases (wm = 0..3), LDS tile Ct[64][136], coalesced stores ----
    unsigned short* Ct = smem;                  // [64][136] = 17408 B
    const int co = tid & 15;                    // col octet for store pass
    const int rr = tid >> 4;                    // row 0..31 within 32-row group
    const int colg = col0 + co * 8;
    const int p = colg / 384;
    const int rem = colg - p * 384;
    const int h = rem >> 6;
    const int d = rem & 63;
    unsigned short* dst = (p == 0) ? qO : ((p == 1) ? kO : vO);

#pragma unroll
    for (int ph = 0; ph < 4; ++ph) {
        if (wm == ph) {
#pragma unroll
            for (int mf = 0; mf < 4; ++mf)
#pragma unroll
                for (int nf = 0; nf < 4; ++nf)
#pragma unroll
                    for (int r = 0; r < 4; ++r)
                        Ct[(mf * 16 + (lane >> 4) * 4 + r) * 136 + wn * 64 + nf * 16 + (lane & 15)] =
                            f2b(acc[mf][nf][r]);
        }
        __syncthreads();
#pragma unroll
        for (int it = 0; it < 2; ++it) {
            const int r_loc = it * 32 + rr;
            const int m = row0 + ph * 64 + r_loc;
            const int b = m >> 8, t = m & 255;
            uint4 val = *(const uint4*)&Ct[r_loc * 136 + co * 8];
            *(uint4*)&dst[(size_t)((b * 6 + h) * 256 + t) * 64 + d] = val;
        }
        __syncthreads();
    }
}

// ---------------- attention ----------------
// block = one (b,h); 512 threads = 8 waves; wave w owns q rows [w*32, w*32+32)
// S^T = K * Q^T via mfma_32x32x16 -> lane owns one q col; V transposed into LDS.
// Ot (epilogue tile) ALIASES Ks — requires the __syncthreads before Ot writes.
// extern shared 70656 B -> 2 blocks/CU (launch_bounds caps VGPR at 128).

__global__ __launch_bounds__(512, 4) void attn_kernel(
    const unsigned short* __restrict__ Qg,   // [B][H][T][D]
    const unsigned short* __restrict__ Kg,   // [B][H][T][D]
    const unsigned short* __restrict__ Vg,   // [B][H][T][D]
    unsigned short* __restrict__ Og)         // [B*T][384], col h*64+d
{
    extern __shared__ __align__(16) unsigned short asmem[];
    unsigned short* Ks = asmem;                 // 256*72 = 18432 elems
    unsigned short* Vs = asmem + 256 * 72;      // 64*264 = 16896 elems
    unsigned short* Ot = asmem;                 // aliases Ks (8*32*72 = 18432 elems)
    const int bh = blockIdx.x;
    const int b = bh / 6, h = bh - b * 6;
    const int tid = threadIdx.x;
    const int lane = tid & 63;
    const int w = tid >> 6;
    const int lo = lane & 31, hi = lane >> 5;

    const unsigned short* kg = Kg + (size_t)bh * 256 * 64;
#pragma unroll
    for (int j = 0; j < 4; ++j) {
        int chunk = tid + 512 * j;               // 2048 chunks of 8 elems
        int key = chunk >> 3, dc = (chunk & 7) * 8;
        *(uint4*)&Ks[key * 72 + dc] = *(const uint4*)&kg[key * 64 + dc];
    }
    // stage V transposed: unit u -> t-pair t2, d-octet dm.  Vs[d][t] = V[t][d]
    {
        const unsigned short* vg = Vg + (size_t)bh * 256 * 64;
        uint32_t* Vs32 = (uint32_t*)Vs;
#pragma unroll
        for (int i = 0; i < 2; ++i) {
            int u = tid + 512 * i;                       // 10-bit unit id
            int t2 = (u & 31) | ((u >> 8) << 5);         // 0..127
            int dm = (u >> 5) & 7;                       // d-octet
            uint4 r0 = *(const uint4*)&vg[(2 * t2 + 0) * 64 + dm * 8];
            uint4 r1 = *(const uint4*)&vg[(2 * t2 + 1) * 64 + dm * 8];
            const unsigned short* e0 = (const unsigned short*)&r0;
            const unsigned short* e1 = (const unsigned short*)&r1;
#pragma unroll
            for (int j = 0; j < 8; ++j)
                Vs32[(dm * 8 + j) * 132 + t2] = (uint32_t)e0[j] | ((uint32_t)e1[j] << 16);
        }
    }
    __syncthreads();

    const int q0 = w * 32;
    const unsigned short* qg = Qg + (size_t)bh * 256 * 64 + (size_t)(q0 + lo) * 64 + hi * 8;
    bf16x8 qF[4];
#pragma unroll
    for (int dc = 0; dc < 4; ++dc) qF[dc] = *(const bf16x8*)(qg + dc * 16);

    float m = -1e30f, ssum = 0.f;
    f32x16 o0, o1;
#pragma unroll
    for (int r = 0; r < 16; ++r) { o0[r] = 0.f; o1[r] = 0.f; }

    for (int kt = 0; kt <= w; ++kt) {
        f32x16 s;
#pragma unroll
        for (int r = 0; r < 16; ++r) s[r] = 0.f;
#pragma unroll
        for (int dc = 0; dc < 4; ++dc) {
            bf16x8 aK = *(const bf16x8*)&Ks[(kt * 32 + lo) * 72 + dc * 16 + hi * 8];
            s = __builtin_amdgcn_mfma_f32_32x32x16_bf16(aK, qF[dc], s, 0, 0, 0);
        }
        float p[16];
        float pmax = -1e30f;
        const bool diag = (kt == w);
#pragma unroll
        for (int r = 0; r < 16; ++r) {
            float sv = s[r] * 0.125f;
            const int keyl = (r & 3) + 8 * (r >> 2) + 4 * hi;
            if (diag && keyl > lo) sv = -1e30f;
            p[r] = sv;
            pmax = fmaxf(pmax, sv);
        }
        pmax = fmaxf(pmax, __shfl_xor(pmax, 32, 64));
        const float mn = fmaxf(m, pmax);
        const float sf = __expf(m - mn);
        m = mn;
        ssum *= sf;
#pragma unroll
        for (int r = 0; r < 16; ++r) { o0[r] *= sf; o1[r] *= sf; }
        float rs = 0.f;
#pragma unroll
        for (int r = 0; r < 16; ++r) { p[r] = __expf(p[r] - m); rs += p[r]; }
        rs += __shfl_xor(rs, 32, 64);
        ssum += rs;

        // redistribute P to PV B-operand layout: lane needs P^T[key=(kc*16 + hi*8 + i)][q=lo]
        union { unsigned short u[16]; bf16x8 v[2]; } P;
        {
            float recv[4];
#pragma unroll
            for (int j2 = 0; j2 < 4; ++j2) {
                float sendv = hi ? p[j2] : p[4 + j2];
                recv[j2] = __shfl_xor(sendv, 32, 64);
            }
#pragma unroll
            for (int i = 0; i < 4; ++i) P.u[i]     = f2b(hi ? recv[i] : p[i]);
#pragma unroll
            for (int i = 0; i < 4; ++i) P.u[4 + i] = f2b(hi ? p[4 + i] : recv[i]);
        }
        {
            float recv[4];
#pragma unroll
            for (int j2 = 0; j2 < 4; ++j2) {
                float sendv = hi ? p[8 + j2] : p[12 + j2];
                recv[j2] = __shfl_xor(sendv, 32, 64);
            }
#pragma unroll
            for (int i = 0; i < 4; ++i) P.u[8 + i]  = f2b(hi ? recv[i] : p[8 + i]);
#pragma unroll
            for (int i = 0; i < 4; ++i) P.u[12 + i] = f2b(hi ? p[12 + i] : recv[i]);
        }

#pragma unroll
        for (int kc = 0; kc < 2; ++kc) {
            bf16x8 aV0 = *(const bf16x8*)&Vs[lo * 264 + kt * 32 + kc * 16 + hi * 8];
            o0 = __builtin_amdgcn_mfma_f32_32x32x16_bf16(aV0, P.v[kc], o0, 0, 0, 0);
            bf16x8 aV1 = *(const bf16x8*)&Vs[(32 + lo) * 264 + kt * 32 + kc * 16 + hi * 8];
            o1 = __builtin_amdgcn_mfma_f32_32x32x16_bf16(aV1, P.v[kc], o1, 0, 0, 0);
        }
    }

    // ---- epilogue: per-wave LDS transpose (Ot aliases Ks!), then coalesced stores ----
    __syncthreads();   // ALL waves must finish reading Ks before Ot overwrites it
    const float inv = 1.f / ssum;
    {
        uint32_t* ot32 = (uint32_t*)&Ot[w * 32 * 72];
#pragma unroll
        for (int g = 0; g < 4; ++g) {
            const int dbase0 = 8 * g + 4 * hi;
            uint32_t w0 = pk2(o0[4 * g + 0] * inv, o0[4 * g + 1] * inv);
            uint32_t w1 = pk2(o0[4 * g + 2] * inv, o0[4 * g + 3] * inv);
            int dw = lo * 36 + (dbase0 >> 1);
            ot32[dw] = w0;
            ot32[dw + 1] = w1;
            uint32_t w2 = pk2(o1[4 * g + 0] * inv, o1[4 * g + 1] * inv);
            uint32_t w3 = pk2(o1[4 * g + 2] * inv, o1[4 * g + 3] * inv);
            int dw1 = lo * 36 + ((32 + dbase0) >> 1);
            ot32[dw1] = w2;
            ot32[dw1 + 1] = w3;
        }
    }
    __syncthreads();
    {
        const unsigned short* ot = &Ot[w * 32 * 72];
        const int q = lane >> 1;                        // 0..31
        const int half = (lane & 1) * 32;               // elem offset 0 / 32
        unsigned short* og = Og + (size_t)(b * 256 + q0 + q) * 384 + h * 64 + half;
#pragma unroll
        for (int jj = 0; jj < 4; ++jj) {
            uint4 val = *(const uint4*)&ot[q * 72 + half + jj * 8];
            *(uint4*)&og[jj * 8] = val;
        }
    }
}

// ---------------- GEMM2: output projection ----------------
// 128x128 tile, BK=32, 3-buffer counted-vmcnt pipeline (pinned), XCD-swizzled (nwg=768),
// T2 XOR-swizzled LDS (same scheme as gemm_qkv).

__global__ __launch_bounds__(256, 3) void gemm_proj(
    const unsigned short* __restrict__ ob,   // [32768][384]
    const unsigned short* __restrict__ wpt,  // [384][384] (pre-transposed)
    const float* __restrict__ bp,            // [384]
    float* __restrict__ out)                 // [32768][384]
{
    __shared__ __align__(16) unsigned short As[3][128 * 32];
    __shared__ __align__(16) unsigned short Bs[3][128 * 32];
    const int tid  = threadIdx.x;
    const int lane = tid & 63;
    const int w    = tid >> 6;
    const int wm = w >> 1, wn = w & 1;

    const int flat = blockIdx.y * 3 + blockIdx.x;
    const int swz = (flat & 7) * 96 + (flat >> 3);
    const int bx = swz % 3, by = swz / 3;
    const int col0 = bx * 128;
    const int row0 = by * 128;

    const unsigned short* Abase = ob  + (size_t)row0 * 384;
    const unsigned short* Bbase = wpt + (size_t)col0 * 384;

    f32x4 acc[4][4];
#pragma unroll
    for (int mf = 0; mf < 4; ++mf)
#pragma unroll
        for (int nf = 0; nf < 4; ++nf)
#pragma unroll
            for (int r = 0; r < 4; ++r) acc[mf][nf][r] = 0.f;

    const int ci0 = tid;
    const int ci1 = tid + 256;
    const int r0c = ci0 >> 2, o0c = (ci0 & 3) ^ ((ci0 >> 3) & 3);
    const int r1c = ci1 >> 2, o1c = (ci1 & 3) ^ ((ci1 >> 3) & 3);
    const unsigned short* aSrc0 = Abase + (size_t)r0c * 384 + o0c * 8;
    const unsigned short* aSrc1 = Abase + (size_t)r1c * 384 + o1c * 8;
    const unsigned short* bSrc0 = Bbase + (size_t)r0c * 384 + o0c * 8;
    const unsigned short* bSrc1 = Bbase + (size_t)r1c * 384 + o1c * 8;
    const int cb = w * 64;

    auto STAGE = [&](int buf, int kt) {
        const int k0_ = kt * 32;
        gload_lds16(aSrc0 + k0_, (unsigned short*)As[buf] + (cb + 0) * 8);
        gload_lds16(bSrc0 + k0_, (unsigned short*)Bs[buf] + (cb + 0) * 8);
        gload_lds16(aSrc1 + k0_, (unsigned short*)As[buf] + (cb + 256) * 8);
        gload_lds16(bSrc1 + k0_, (unsigned short*)Bs[buf] + (cb + 256) * 8);
    };

    const int fr = lane & 15;
    const int oc = (lane >> 4) ^ ((fr >> 1) & 3);

    auto COMPUTE = [&](int buf) {
        const unsigned short* A = As[buf];
        const unsigned short* B = Bs[buf];
        bf16x8 aF[4], bF[4];
#pragma unroll
        for (int mf = 0; mf < 4; ++mf)
            aF[mf] = *(const bf16x8*)&A[(wm * 64 + mf * 16 + fr) * 32 + oc * 8];
#pragma unroll
        for (int nf = 0; nf < 4; ++nf)
            bF[nf] = *(const bf16x8*)&B[(wn * 64 + nf * 16 + fr) * 32 + oc * 8];
#pragma unroll
        for (int mf = 0; mf < 4; ++mf)
#pragma unroll
            for (int nf = 0; nf < 4; ++nf)
                acc[mf][nf] = __builtin_amdgcn_mfma_f32_16x16x32_bf16(aF[mf], bF[nf], acc[mf][nf], 0, 0, 0);
    };

    STAGE(0, 0);
    STAGE(1, 1);
    SBAR0();
    int bufS = 2, bufC = 0;
    for (int t = 0; t < 10; ++t) {
        STAGE(bufS, t + 2);
        bufS = (bufS == 2) ? 0 : bufS + 1;
        SBAR0();
        asm volatile("s_waitcnt vmcnt(8)" ::: "memory");
        SBAR0();
        __builtin_amdgcn_s_barrier();
        SBAR0();
        COMPUTE(bufC);
        bufC = (bufC == 2) ? 0 : bufC + 1;
        SBAR0();
        __builtin_amdgcn_s_barrier();
        SBAR0();
    }
    asm volatile("s_waitcnt vmcnt(4)" ::: "memory");
    SBAR0();
    __builtin_amdgcn_s_barrier();
    SBAR0();
    COMPUTE(1);
    SBAR0();
    __builtin_amdgcn_s_barrier();
    SBAR0();
    asm volatile("s_waitcnt vmcnt(0)" ::: "memory");
    SBAR0();
    __builtin_amdgcn_s_barrier();
    SBAR0();
    COMPUTE(2);

#pragma unroll
    for (int nf = 0; nf < 4; ++nf) {
        const int col = col0 + wn * 64 + nf * 16 + (lane & 15);
        const float bias = bp[col];
#pragma unroll
        for (int mf = 0; mf < 4; ++mf) {
            const int mbase = row0 + wm * 64 + mf * 16 + ((lane >> 4) * 4);
#pragma unroll
            for (int r = 0; r < 4; ++r) {
                const int mrow = mbase + r;
                out[(size_t)mrow * 384 + col] = acc[mf][nf][r] + bias;
            }
        }
    }
}

// ---------------- launch ----------------

extern "C" void kernel_launch(void* const* d_in, const int* in_sizes, int n_in,
                              void* d_out, int out_size, void* d_ws, size_t ws_size,
                              hipStream_t stream) {
    const float* x  = (const float*)d_in[0];
    const float* Wq = (const float*)d_in[1];
    const float* Wk = (const float*)d_in[2];
    const float* Wv = (const float*)d_in[3];
    const float* Wp = (const float*)d_in[4];
    const float* bp = (const float*)d_in[5];
    float* out = (float*)d_out;

    char* ws = (char*)d_ws;
    unsigned short* xb  = (unsigned short*)(ws);              // 25165824 B (reused as attn output O)
    unsigned short* qb  = (unsigned short*)(ws + 25165824);   // 25165824 B
    unsigned short* kb  = (unsigned short*)(ws + 50331648);   // 25165824 B
    unsigned short* vb  = (unsigned short*)(ws + 75497472);   // 25165824 B
    unsigned short* wt  = (unsigned short*)(ws + 100663296);  // 884736 B (1152x384)
    unsigned short* wpt = (unsigned short*)(ws + 101548032);  // 294912 B (384x384)

    cvt_x_kernel<<<6144, 256, 0, stream>>>(x, xb, 1572864);
    cvt_w_kernel<<<2304, 256, 0, stream>>>(Wq, Wk, Wv, Wp, wt, wpt);
    gemm_qkv<<<dim3(9, 128), 512, 73728, stream>>>(xb, wt, qb, kb, vb);
    attn_kernel<<<768, 512, 70656, stream>>>(qb, kb, vb, xb);
    gemm_proj<<<dim3(3, 256), 256, 0, stream>>>(xb, wpt, bp, out);
}

// Round 11
// 109.598 us; speedup vs baseline: 1.0078x; 1.0078x over previous
//
#include <hip/hip_runtime.h>
#include <stdint.h>

// B=128, T=256, C=384, H=6, D=64;  M = B*T = 32768
// GEMM1: x f32 [32768,384] x wt^T[1152,384] -> Q,K,V [B,H,T,D] (bf16)
//        128x128 tile, BK=32, 3-buf counted-vmcnt pipeline (pinned), XCD swizzle.
//        A staged as f32 via global_load_lds (fused conversion at frag read,
//        v_cvt_pk_bf16_f32); quad-XOR LDS swizzle on A, oct-XOR on B.
// attn : per (b,h), 8 waves x 32 q rows, swapped-QK^T flash, causal; Ot aliases Ks
// GEMM2: O[32768,384] x wpt[384,384] + bp -> out f32 (128x128, round-9 config)

typedef __attribute__((ext_vector_type(8))) short bf16x8;
typedef __attribute__((ext_vector_type(4))) float f32x4;
typedef __attribute__((ext_vector_type(16))) float f32x16;

__device__ __forceinline__ unsigned short f2b(float f) {
    union { float f; unsigned int u; } v; v.f = f;
    unsigned int u = v.u + 0x7fffu + ((v.u >> 16) & 1u);
    return (unsigned short)(u >> 16);
}

__device__ __forceinline__ unsigned int pk2(float lo, float hi) {
    return (unsigned int)f2b(lo) | ((unsigned int)f2b(hi) << 16);
}

__device__ __forceinline__ uint32_t cvtpk(float lo, float hi) {
    uint32_t r;
    asm("v_cvt_pk_bf16_f32 %0, %1, %2" : "=v"(r) : "v"(lo), "v"(hi));
    return r;
}

__device__ __forceinline__ void gload_lds16(const void* g, void* lds) {
    auto gp = reinterpret_cast<const __attribute__((address_space(1))) uint32_t*>(
        reinterpret_cast<uintptr_t>(g));
    auto lp = reinterpret_cast<__attribute__((address_space(3))) uint32_t*>(
        reinterpret_cast<uintptr_t>(lds));
    __builtin_amdgcn_global_load_lds(gp, lp, 16, 0, 0);
}

#define SBAR0() __builtin_amdgcn_sched_barrier(0)

// ---------------- conversion kernel (weights only) ----------------

// wt[j][c] = W_{p}[h][c][d]  (j = p*384 + h*64 + d), 1152x384
// wpt[n][c] = Wp[c][n], 384x384
__global__ void cvt_w_kernel(const float* __restrict__ Wq, const float* __restrict__ Wk,
                             const float* __restrict__ Wv, const float* __restrict__ Wp,
                             unsigned short* __restrict__ wt, unsigned short* __restrict__ wpt) {
    int i = blockIdx.x * 256 + threadIdx.x;
    if (i >= 589824) return;
    if (i < 442368) {
        int j = i / 384, c = i - j * 384;
        int p = j / 384, rem = j - p * 384;
        int h = rem >> 6, d = rem & 63;
        const float* W = (p == 0) ? Wq : ((p == 1) ? Wk : Wv);
        wt[i] = f2b(W[(size_t)(h * 384 + c) * 64 + d]);
    } else {
        int i2 = i - 442368;
        int n = i2 / 384, c = i2 - n * 384;
        wpt[i2] = f2b(Wp[(size_t)c * 384 + n]);
    }
}

// ---------------- GEMM1: qkv projections (fused x conversion) ----------------
// 128x128 tile, BK=32. A tile: f32 [128][32] = 16 KiB; B tile: bf16 [128][32] = 8 KiB.
// 3 buffers each (72 KiB). 6 gload_lds per STAGE -> vmcnt(12)/(6)/(0).
// A swizzle: quad slot ql = qg ^ (row&7)  (quad = 4 f32 = 16 B; row = 8 quads).
// B swizzle: oct  slot ol = og ^ ((row>>1)&3) (oct = 8 bf16 = 16 B; row = 4 octs).

__global__ __launch_bounds__(256, 2) void gemm_qkv(
    const float* __restrict__ x,             // [32768][384] f32
    const unsigned short* __restrict__ wt,   // [1152][384] bf16
    unsigned short* __restrict__ qO,         // [B][H][T][D]
    unsigned short* __restrict__ kO,         // [B][H][T][D]
    unsigned short* __restrict__ vO)         // [B][H][T][D]
{
    extern __shared__ __align__(16) unsigned short smem[];  // 73728 B
    float*          Af = (float*)smem;                    // [3][4096] f32  (48 KiB)
    unsigned short* Bf = smem + 24576;                    // [3][4096] bf16 (24 KiB)

    const int tid  = threadIdx.x;
    const int lane = tid & 63;
    const int w    = tid >> 6;
    const int wm = w >> 1, wn = w & 1;          // 2M x 2N wave grid

    // XCD-aware swizzle: nwg = 2304 = 8*288
    const int flat = blockIdx.y * 9 + blockIdx.x;
    const int swz = (flat & 7) * 288 + (flat >> 3);
    const int bx = swz % 9, by = swz / 9;
    const int col0 = bx * 128;
    const int row0 = by * 128;

    const float* Abase = x + (size_t)row0 * 384;
    const unsigned short* Bbase = wt + (size_t)col0 * 384;

    f32x4 acc[4][4];
#pragma unroll
    for (int mf = 0; mf < 4; ++mf)
#pragma unroll
        for (int nf = 0; nf < 4; ++nf)
#pragma unroll
            for (int r = 0; r < 4; ++r) acc[mf][nf][r] = 0.f;

    // A: 1024 quads (128 rows x 8); chunk ci: row = ci>>3, global quad = (ci&7)^((ci>>3)&7)
    const float* aSrc[4];
#pragma unroll
    for (int j = 0; j < 4; ++j) {
        const int ci = tid + 256 * j;
        aSrc[j] = Abase + (size_t)(ci >> 3) * 384 + ((ci & 7) ^ ((ci >> 3) & 7)) * 4;
    }
    // B: 512 octs (128 rows x 4); chunk ci: row = ci>>2, global oct = (ci&3)^((ci>>3)&3)
    const int bi0 = tid, bi1 = tid + 256;
    const unsigned short* bSrc0 = Bbase + (size_t)(bi0 >> 2) * 384 + ((bi0 & 3) ^ ((bi0 >> 3) & 3)) * 8;
    const unsigned short* bSrc1 = Bbase + (size_t)(bi1 >> 2) * 384 + ((bi1 & 3) ^ ((bi1 >> 3) & 3)) * 8;
    const int cb = w * 64;  // wave-uniform chunk base

    auto STAGE = [&](int buf, int kt) {
        const int k0_ = kt * 32;
#pragma unroll
        for (int j = 0; j < 4; ++j)
            gload_lds16(aSrc[j] + k0_, Af + buf * 4096 + (cb + 256 * j) * 4);
        gload_lds16(bSrc0 + k0_, Bf + buf * 4096 + (cb + 0) * 8);
        gload_lds16(bSrc1 + k0_, Bf + buf * 4096 + (cb + 256) * 8);
    };

    const int fr  = lane & 15;
    const int oc  = lane >> 4;                      // K-octet 0..3 (8 elems)
    const int qlA0 = (2 * oc)     ^ (fr & 7);       // A quad slots (frag bases x16)
    const int qlA1 = (2 * oc + 1) ^ (fr & 7);
    const int ocB  = oc ^ ((fr >> 1) & 3);          // B oct slot

    auto COMPUTE = [&](int buf) {
        const float* A = Af + buf * 4096;
        const unsigned short* B = Bf + buf * 4096;
        bf16x8 aF[4], bF[4];
#pragma unroll
        for (int mf = 0; mf < 4; ++mf) {
            const int rowA = wm * 64 + mf * 16 + fr;
            f32x4 F0 = *(const f32x4*)&A[rowA * 32 + qlA0 * 4];
            f32x4 F1 = *(const f32x4*)&A[rowA * 32 + qlA1 * 4];
            union { uint32_t u[4]; bf16x8 v; } pk;
            pk.u[0] = cvtpk(F0[0], F0[1]);
            pk.u[1] = cvtpk(F0[2], F0[3]);
            pk.u[2] = cvtpk(F1[0], F1[1]);
            pk.u[3] = cvtpk(F1[2], F1[3]);
            aF[mf] = pk.v;
        }
#pragma unroll
        for (int nf = 0; nf < 4; ++nf)
            bF[nf] = *(const bf16x8*)&B[(wn * 64 + nf * 16 + fr) * 32 + ocB * 8];
#pragma unroll
        for (int mf = 0; mf < 4; ++mf)
#pragma unroll
            for (int nf = 0; nf < 4; ++nf)
                acc[mf][nf] = __builtin_amdgcn_mfma_f32_16x16x32_bf16(aF[mf], bF[nf], acc[mf][nf], 0, 0, 0);
    };

    STAGE(0, 0);
    STAGE(1, 1);
    SBAR0();
    int bufS = 2, bufC = 0;
    for (int t = 0; t < 10; ++t) {
        STAGE(bufS, t + 2);
        bufS = (bufS == 2) ? 0 : bufS + 1;
        SBAR0();
        asm volatile("s_waitcnt vmcnt(12)" ::: "memory");
        SBAR0();
        __builtin_amdgcn_s_barrier();
        SBAR0();
        COMPUTE(bufC);
        bufC = (bufC == 2) ? 0 : bufC + 1;
        SBAR0();
        __builtin_amdgcn_s_barrier();
        SBAR0();
    }
    asm volatile("s_waitcnt vmcnt(6)" ::: "memory");
    SBAR0();
    __builtin_amdgcn_s_barrier();
    SBAR0();
    COMPUTE(1);
    SBAR0();
    __builtin_amdgcn_s_barrier();
    SBAR0();
    asm volatile("s_waitcnt vmcnt(0)" ::: "memory");
    SBAR0();
    __builtin_amdgcn_s_barrier();
    SBAR0();
    COMPUTE(2);
    __syncthreads();   // full drain before smem reuse as epilogue tile

    // ---- epilogue: 2 phases (wm = 0,1), LDS tile Ct[64][136], coalesced stores ----
    unsigned short* Ct = smem;                  // [64][136] = 17408 B
    const int co = tid & 15;                    // col octet for store pass
    const int rr = tid >> 4;                    // row within 16-row group
    const int colg = col0 + co * 8;
    const int p = colg / 384;
    const int rem = colg - p * 384;
    const int h = rem >> 6;
    const int d = rem & 63;
    unsigned short* dst = (p == 0) ? qO : ((p == 1) ? kO : vO);

#pragma unroll
    for (int ph = 0; ph < 2; ++ph) {
        if (wm == ph) {
#pragma unroll
            for (int mf = 0; mf < 4; ++mf)
#pragma unroll
                for (int nf = 0; nf < 4; ++nf)
#pragma unroll
                    for (int r = 0; r < 4; ++r)
                        Ct[(mf * 16 + (lane >> 4) * 4 + r) * 136 + wn * 64 + nf * 16 + (lane & 15)] =
                            f2b(acc[mf][nf][r]);
        }
        __syncthreads();
#pragma unroll
        for (int it = 0; it < 4; ++it) {
            const int r_loc = it * 16 + rr;
            const int m = row0 + ph * 64 + r_loc;
            const int b = m >> 8, t = m & 255;
            uint4 val = *(const uint4*)&Ct[r_loc * 136 + co * 8];
            *(uint4*)&dst[(size_t)((b * 6 + h) * 256 + t) * 64 + d] = val;
        }
        __syncthreads();
    }
}

// ---------------- attention ----------------
// block = one (b,h); 512 threads = 8 waves; wave w owns q rows [w*32, w*32+32)
// S^T = K * Q^T via mfma_32x32x16 -> lane owns one q col; V transposed into LDS.
// Ot (epilogue tile) ALIASES Ks — requires the __syncthreads before Ot writes.
// extern shared 70656 B -> 2 blocks/CU (launch_bounds caps VGPR at 128).

__global__ __launch_bounds__(512, 4) void attn_kernel(
    const unsigned short* __restrict__ Qg,   // [B][H][T][D]
    const unsigned short* __restrict__ Kg,   // [B][H][T][D]
    const unsigned short* __restrict__ Vg,   // [B][H][T][D]
    unsigned short* __restrict__ Og)         // [B*T][384], col h*64+d
{
    extern __shared__ __align__(16) unsigned short asmem[];
    unsigned short* Ks = asmem;                 // 256*72 = 18432 elems
    unsigned short* Vs = asmem + 256 * 72;      // 64*264 = 16896 elems
    unsigned short* Ot = asmem;                 // aliases Ks (8*32*72 = 18432 elems)
    const int bh = blockIdx.x;
    const int b = bh / 6, h = bh - b * 6;
    const int tid = threadIdx.x;
    const int lane = tid & 63;
    const int w = tid >> 6;
    const int lo = lane & 31, hi = lane >> 5;

    const unsigned short* kg = Kg + (size_t)bh * 256 * 64;
#pragma unroll
    for (int j = 0; j < 4; ++j) {
        int chunk = tid + 512 * j;               // 2048 chunks of 8 elems
        int key = chunk >> 3, dc = (chunk & 7) * 8;
        *(uint4*)&Ks[key * 72 + dc] = *(const uint4*)&kg[key * 64 + dc];
    }
    // stage V transposed: unit u -> t-pair t2, d-octet dm.  Vs[d][t] = V[t][d]
    {
        const unsigned short* vg = Vg + (size_t)bh * 256 * 64;
        uint32_t* Vs32 = (uint32_t*)Vs;
#pragma unroll
        for (int i = 0; i < 2; ++i) {
            int u = tid + 512 * i;                       // 10-bit unit id
            int t2 = (u & 31) | ((u >> 8) << 5);         // 0..127
            int dm = (u >> 5) & 7;                       // d-octet
            uint4 r0 = *(const uint4*)&vg[(2 * t2 + 0) * 64 + dm * 8];
            uint4 r1 = *(const uint4*)&vg[(2 * t2 + 1) * 64 + dm * 8];
            const unsigned short* e0 = (const unsigned short*)&r0;
            const unsigned short* e1 = (const unsigned short*)&r1;
#pragma unroll
            for (int j = 0; j < 8; ++j)
                Vs32[(dm * 8 + j) * 132 + t2] = (uint32_t)e0[j] | ((uint32_t)e1[j] << 16);
        }
    }
    __syncthreads();

    const int q0 = w * 32;
    const unsigned short* qg = Qg + (size_t)bh * 256 * 64 + (size_t)(q0 + lo) * 64 + hi * 8;
    bf16x8 qF[4];
#pragma unroll
    for (int dc = 0; dc < 4; ++dc) qF[dc] = *(const bf16x8*)(qg + dc * 16);

    float m = -1e30f, ssum = 0.f;
    f32x16 o0, o1;
#pragma unroll
    for (int r = 0; r < 16; ++r) { o0[r] = 0.f; o1[r] = 0.f; }

    for (int kt = 0; kt <= w; ++kt) {
        f32x16 s;
#pragma unroll
        for (int r = 0; r < 16; ++r) s[r] = 0.f;
#pragma unroll
        for (int dc = 0; dc < 4; ++dc) {
            bf16x8 aK = *(const bf16x8*)&Ks[(kt * 32 + lo) * 72 + dc * 16 + hi * 8];
            s = __builtin_amdgcn_mfma_f32_32x32x16_bf16(aK, qF[dc], s, 0, 0, 0);
        }
        float p[16];
        float pmax = -1e30f;
        const bool diag = (kt == w);
#pragma unroll
        for (int r = 0; r < 16; ++r) {
            float sv = s[r] * 0.125f;
            const int keyl = (r & 3) + 8 * (r >> 2) + 4 * hi;
            if (diag && keyl > lo) sv = -1e30f;
            p[r] = sv;
            pmax = fmaxf(pmax, sv);
        }
        pmax = fmaxf(pmax, __shfl_xor(pmax, 32, 64));
        const float mn = fmaxf(m, pmax);
        const float sf = __expf(m - mn);
        m = mn;
        ssum *= sf;
#pragma unroll
        for (int r = 0; r < 16; ++r) { o0[r] *= sf; o1[r] *= sf; }
        float rs = 0.f;
#pragma unroll
        for (int r = 0; r < 16; ++r) { p[r] = __expf(p[r] - m); rs += p[r]; }
        rs += __shfl_xor(rs, 32, 64);
        ssum += rs;

        // redistribute P to PV B-operand layout: lane needs P^T[key=(kc*16 + hi*8 + i)][q=lo]
        union { unsigned short u[16]; bf16x8 v[2]; } P;
        {
            float recv[4];
#pragma unroll
            for (int j2 = 0; j2 < 4; ++j2) {
                float sendv = hi ? p[j2] : p[4 + j2];
                recv[j2] = __shfl_xor(sendv, 32, 64);
            }
#pragma unroll
            for (int i = 0; i < 4; ++i) P.u[i]     = f2b(hi ? recv[i] : p[i]);
#pragma unroll
            for (int i = 0; i < 4; ++i) P.u[4 + i] = f2b(hi ? p[4 + i] : recv[i]);
        }
        {
            float recv[4];
#pragma unroll
            for (int j2 = 0; j2 < 4; ++j2) {
                float sendv = hi ? p[8 + j2] : p[12 + j2];
                recv[j2] = __shfl_xor(sendv, 32, 64);
            }
#pragma unroll
            for (int i = 0; i < 4; ++i) P.u[8 + i]  = f2b(hi ? recv[i] : p[8 + i]);
#pragma unroll
            for (int i = 0; i < 4; ++i) P.u[12 + i] = f2b(hi ? p[12 + i] : recv[i]);
        }

#pragma unroll
        for (int kc = 0; kc < 2; ++kc) {
            bf16x8 aV0 = *(const bf16x8*)&Vs[lo * 264 + kt * 32 + kc * 16 + hi * 8];
            o0 = __builtin_amdgcn_mfma_f32_32x32x16_bf16(aV0, P.v[kc], o0, 0, 0, 0);
            bf16x8 aV1 = *(const bf16x8*)&Vs[(32 + lo) * 264 + kt * 32 + kc * 16 + hi * 8];
            o1 = __builtin_amdgcn_mfma_f32_32x32x16_bf16(aV1, P.v[kc], o1, 0, 0, 0);
        }
    }

    // ---- epilogue: per-wave LDS transpose (Ot aliases Ks!), then coalesced stores ----
    __syncthreads();   // ALL waves must finish reading Ks before Ot overwrites it
    const float inv = 1.f / ssum;
    {
        uint32_t* ot32 = (uint32_t*)&Ot[w * 32 * 72];
#pragma unroll
        for (int g = 0; g < 4; ++g) {
            const int dbase0 = 8 * g + 4 * hi;
            uint32_t w0 = pk2(o0[4 * g + 0] * inv, o0[4 * g + 1] * inv);
            uint32_t w1 = pk2(o0[4 * g + 2] * inv, o0[4 * g + 3] * inv);
            int dw = lo * 36 + (dbase0 >> 1);
            ot32[dw] = w0;
            ot32[dw + 1] = w1;
            uint32_t w2 = pk2(o1[4 * g + 0] * inv, o1[4 * g + 1] * inv);
            uint32_t w3 = pk2(o1[4 * g + 2] * inv, o1[4 * g + 3] * inv);
            int dw1 = lo * 36 + ((32 + dbase0) >> 1);
            ot32[dw1] = w2;
            ot32[dw1 + 1] = w3;
        }
    }
    __syncthreads();
    {
        const unsigned short* ot = &Ot[w * 32 * 72];
        const int q = lane >> 1;                        // 0..31
        const int half = (lane & 1) * 32;               // elem offset 0 / 32
        unsigned short* og = Og + (size_t)(b * 256 + q0 + q) * 384 + h * 64 + half;
#pragma unroll
        for (int jj = 0; jj < 4; ++jj) {
            uint4 val = *(const uint4*)&ot[q * 72 + half + jj * 8];
            *(uint4*)&og[jj * 8] = val;
        }
    }
}

// ---------------- GEMM2: output projection ----------------
// 128x128 tile, BK=32, 3-buffer counted-vmcnt pipeline (pinned), XCD-swizzled (nwg=768),
// T2 XOR-swizzled LDS.

__global__ __launch_bounds__(256, 3) void gemm_proj(
    const unsigned short* __restrict__ ob,   // [32768][384]
    const unsigned short* __restrict__ wpt,  // [384][384] (pre-transposed)
    const float* __restrict__ bp,            // [384]
    float* __restrict__ out)                 // [32768][384]
{
    __shared__ __align__(16) unsigned short As[3][128 * 32];
    __shared__ __align__(16) unsigned short Bs[3][128 * 32];
    const int tid  = threadIdx.x;
    const int lane = tid & 63;
    const int w    = tid >> 6;
    const int wm = w >> 1, wn = w & 1;

    const int flat = blockIdx.y * 3 + blockIdx.x;
    const int swz = (flat & 7) * 96 + (flat >> 3);
    const int bx = swz % 3, by = swz / 3;
    const int col0 = bx * 128;
    const int row0 = by * 128;

    const unsigned short* Abase = ob  + (size_t)row0 * 384;
    const unsigned short* Bbase = wpt + (size_t)col0 * 384;

    f32x4 acc[4][4];
#pragma unroll
    for (int mf = 0; mf < 4; ++mf)
#pragma unroll
        for (int nf = 0; nf < 4; ++nf)
#pragma unroll
            for (int r = 0; r < 4; ++r) acc[mf][nf][r] = 0.f;

    const int ci0 = tid;
    const int ci1 = tid + 256;
    const int r0c = ci0 >> 2, o0c = (ci0 & 3) ^ ((ci0 >> 3) & 3);
    const int r1c = ci1 >> 2, o1c = (ci1 & 3) ^ ((ci1 >> 3) & 3);
    const unsigned short* aSrc0 = Abase + (size_t)r0c * 384 + o0c * 8;
    const unsigned short* aSrc1 = Abase + (size_t)r1c * 384 + o1c * 8;
    const unsigned short* bSrc0 = Bbase + (size_t)r0c * 384 + o0c * 8;
    const unsigned short* bSrc1 = Bbase + (size_t)r1c * 384 + o1c * 8;
    const int cb = w * 64;

    auto STAGE = [&](int buf, int kt) {
        const int k0_ = kt * 32;
        gload_lds16(aSrc0 + k0_, (unsigned short*)As[buf] + (cb + 0) * 8);
        gload_lds16(bSrc0 + k0_, (unsigned short*)Bs[buf] + (cb + 0) * 8);
        gload_lds16(aSrc1 + k0_, (unsigned short*)As[buf] + (cb + 256) * 8);
        gload_lds16(bSrc1 + k0_, (unsigned short*)Bs[buf] + (cb + 256) * 8);
    };

    const int fr = lane & 15;
    const int oc = (lane >> 4) ^ ((fr >> 1) & 3);

    auto COMPUTE = [&](int buf) {
        const unsigned short* A = As[buf];
        const unsigned short* B = Bs[buf];
        bf16x8 aF[4], bF[4];
#pragma unroll
        for (int mf = 0; mf < 4; ++mf)
            aF[mf] = *(const bf16x8*)&A[(wm * 64 + mf * 16 + fr) * 32 + oc * 8];
#pragma unroll
        for (int nf = 0; nf < 4; ++nf)
            bF[nf] = *(const bf16x8*)&B[(wn * 64 + nf * 16 + fr) * 32 + oc * 8];
#pragma unroll
        for (int mf = 0; mf < 4; ++mf)
#pragma unroll
            for (int nf = 0; nf < 4; ++nf)
                acc[mf][nf] = __builtin_amdgcn_mfma_f32_16x16x32_bf16(aF[mf], bF[nf], acc[mf][nf], 0, 0, 0);
    };

    STAGE(0, 0);
    STAGE(1, 1);
    SBAR0();
    int bufS = 2, bufC = 0;
    for (int t = 0; t < 10; ++t) {
        STAGE(bufS, t + 2);
        bufS = (bufS == 2) ? 0 : bufS + 1;
        SBAR0();
        asm volatile("s_waitcnt vmcnt(8)" ::: "memory");
        SBAR0();
        __builtin_amdgcn_s_barrier();
        SBAR0();
        COMPUTE(bufC);
        bufC = (bufC == 2) ? 0 : bufC + 1;
        SBAR0();
        __builtin_amdgcn_s_barrier();
        SBAR0();
    }
    asm volatile("s_waitcnt vmcnt(4)" ::: "memory");
    SBAR0();
    __builtin_amdgcn_s_barrier();
    SBAR0();
    COMPUTE(1);
    SBAR0();
    __builtin_amdgcn_s_barrier();
    SBAR0();
    asm volatile("s_waitcnt vmcnt(0)" ::: "memory");
    SBAR0();
    __builtin_amdgcn_s_barrier();
    SBAR0();
    COMPUTE(2);

#pragma unroll
    for (int nf = 0; nf < 4; ++nf) {
        const int col = col0 + wn * 64 + nf * 16 + (lane & 15);
        const float bias = bp[col];
#pragma unroll
        for (int mf = 0; mf < 4; ++mf) {
            const int mbase = row0 + wm * 64 + mf * 16 + ((lane >> 4) * 4);
#pragma unroll
            for (int r = 0; r < 4; ++r) {
                const int mrow = mbase + r;
                out[(size_t)mrow * 384 + col] = acc[mf][nf][r] + bias;
            }
        }
    }
}

// ---------------- launch ----------------

extern "C" void kernel_launch(void* const* d_in, const int* in_sizes, int n_in,
                              void* d_out, int out_size, void* d_ws, size_t ws_size,
                              hipStream_t stream) {
    const float* x  = (const float*)d_in[0];
    const float* Wq = (const float*)d_in[1];
    const float* Wk = (const float*)d_in[2];
    const float* Wv = (const float*)d_in[3];
    const float* Wp = (const float*)d_in[4];
    const float* bp = (const float*)d_in[5];
    float* out = (float*)d_out;

    char* ws = (char*)d_ws;
    unsigned short* ob  = (unsigned short*)(ws);              // 25165824 B (attn output O)
    unsigned short* qb  = (unsigned short*)(ws + 25165824);   // 25165824 B
    unsigned short* kb  = (unsigned short*)(ws + 50331648);   // 25165824 B
    unsigned short* vb  = (unsigned short*)(ws + 75497472);   // 25165824 B
    unsigned short* wt  = (unsigned short*)(ws + 100663296);  // 884736 B (1152x384)
    unsigned short* wpt = (unsigned short*)(ws + 101548032);  // 294912 B (384x384)

    cvt_w_kernel<<<2304, 256, 0, stream>>>(Wq, Wk, Wv, Wp, wt, wpt);
    gemm_qkv<<<dim3(9, 256), 256, 73728, stream>>>(x, wt, qb, kb, vb);
    attn_kernel<<<768, 512, 70656, stream>>>(qb, kb, vb, ob);
    gemm_proj<<<dim3(3, 256), 256, 0, stream>>>(ob, wpt, bp, out);
}

// Round 12
// 105.082 us; speedup vs baseline: 1.0511x; 1.0430x over previous
//
#include <hip/hip_runtime.h>
#include <stdint.h>

// B=128, T=256, C=384, H=6, D=64;  M = B*T = 32768
// GEMM1: x f32 [32768,384] (fused cvt via reg-staging + v_cvt_pk_bf16_f32)
//        x wt^T[1152,384] -> Q,K,V [B,H,T,D] bf16. 128x128, BK=32, 2-buf sync loop.
// attn : per (b,h), 8 waves x 32 q rows, swapped-QK^T flash, causal; Ot aliases Ks;
//        defer-max rescale (THR=8) + setprio around MFMA clusters.
// GEMM2: O[32768,384] x wpt[384,384] + bp -> out f32 (pinned counted-vmcnt + T2)

typedef __attribute__((ext_vector_type(8))) short bf16x8;
typedef __attribute__((ext_vector_type(4))) float f32x4;
typedef __attribute__((ext_vector_type(16))) float f32x16;

__device__ __forceinline__ unsigned short f2b(float f) {
    union { float f; unsigned int u; } v; v.f = f;
    unsigned int u = v.u + 0x7fffu + ((v.u >> 16) & 1u);
    return (unsigned short)(u >> 16);
}

__device__ __forceinline__ unsigned int pk2(float lo, float hi) {
    return (unsigned int)f2b(lo) | ((unsigned int)f2b(hi) << 16);
}

__device__ __forceinline__ uint32_t cvtpk(float lo, float hi) {
    uint32_t r;
    asm("v_cvt_pk_bf16_f32 %0, %1, %2" : "=v"(r) : "v"(lo), "v"(hi));
    return r;
}

__device__ __forceinline__ void gload_lds16(const void* g, void* lds) {
    auto gp = reinterpret_cast<const __attribute__((address_space(1))) uint32_t*>(
        reinterpret_cast<uintptr_t>(g));
    auto lp = reinterpret_cast<__attribute__((address_space(3))) uint32_t*>(
        reinterpret_cast<uintptr_t>(lds));
    __builtin_amdgcn_global_load_lds(gp, lp, 16, 0, 0);
}

#define SBAR0() __builtin_amdgcn_sched_barrier(0)

// ---------------- conversion kernel (weights only) ----------------

// wt[j][c] = W_{p}[h][c][d]  (j = p*384 + h*64 + d), 1152x384
// wpt[n][c] = Wp[c][n], 384x384
__global__ void cvt_w_kernel(const float* __restrict__ Wq, const float* __restrict__ Wk,
                             const float* __restrict__ Wv, const float* __restrict__ Wp,
                             unsigned short* __restrict__ wt, unsigned short* __restrict__ wpt) {
    int i = blockIdx.x * 256 + threadIdx.x;
    if (i >= 589824) return;
    if (i < 442368) {
        int j = i / 384, c = i - j * 384;
        int p = j / 384, rem = j - p * 384;
        int h = rem >> 6, d = rem & 63;
        const float* W = (p == 0) ? Wq : ((p == 1) ? Wk : Wv);
        wt[i] = f2b(W[(size_t)(h * 384 + c) * 64 + d]);
    } else {
        int i2 = i - 442368;
        int n = i2 / 384, c = i2 - n * 384;
        wpt[i2] = f2b(Wp[(size_t)c * 384 + n]);
    }
}

// ---------------- GEMM1: qkv projections (fused x conversion) ----------------
// 128x128 tile, BK=32, 2 LDS buffers, __syncthreads loop.
// A staged via registers (f32 load -> v_cvt_pk_bf16_f32 -> ds_write), B via global_load_lds.

__global__ __launch_bounds__(256, 4) void gemm_qkv(
    const float* __restrict__ x,             // [32768][384] f32
    const unsigned short* __restrict__ wt,   // [1152][384] bf16
    unsigned short* __restrict__ qO,         // [B][H][T][D]
    unsigned short* __restrict__ kO,         // [B][H][T][D]
    unsigned short* __restrict__ vO)         // [B][H][T][D]
{
    extern __shared__ __align__(16) unsigned short smem[];  // 32768 B
    unsigned short* As0 = smem;            // [4096]
    unsigned short* As1 = smem + 4096;
    unsigned short* Bs0 = smem + 8192;
    unsigned short* Bs1 = smem + 12288;

    const int tid  = threadIdx.x;
    const int lane = tid & 63;
    const int w    = tid >> 6;
    const int wm = w >> 1, wn = w & 1;          // 2M x 2N wave grid

    // XCD-aware swizzle: nwg = 2304 = 8*288
    const int flat = blockIdx.y * 9 + blockIdx.x;
    const int swz = (flat & 7) * 288 + (flat >> 3);
    const int bx = swz % 9, by = swz / 9;
    const int col0 = bx * 128;
    const int row0 = by * 128;

    f32x4 acc[4][4];
#pragma unroll
    for (int mf = 0; mf < 4; ++mf)
#pragma unroll
        for (int nf = 0; nf < 4; ++nf)
#pragma unroll
            for (int r = 0; r < 4; ++r) acc[mf][nf][r] = 0.f;

    // chunks of 8 elems: 128*32/8 = 512 chunks, 2 per thread
    const int ci0 = tid;
    const int ci1 = tid + 256;
    const float* aS0 = x + (size_t)(row0 + (ci0 >> 2)) * 384 + (ci0 & 3) * 8;
    const float* aS1 = x + (size_t)(row0 + (ci1 >> 2)) * 384 + (ci1 & 3) * 8;
    const unsigned short* bS0 = wt + (size_t)(col0 + (ci0 >> 2)) * 384 + (ci0 & 3) * 8;
    const unsigned short* bS1 = wt + (size_t)(col0 + (ci1 >> 2)) * 384 + (ci1 & 3) * 8;
    const int cb = w * 64;  // wave-uniform chunk base

    float4 aReg0, aReg1, aReg2, aReg3;
    auto LOADA = [&](int kt) {
        const float* p0 = aS0 + kt * 32;
        const float* p1 = aS1 + kt * 32;
        aReg0 = *(const float4*)(p0);
        aReg1 = *(const float4*)(p0 + 4);
        aReg2 = *(const float4*)(p1);
        aReg3 = *(const float4*)(p1 + 4);
    };
    auto WRITEA = [&](unsigned short* As) {
        uint4 w0, w1;
        w0.x = cvtpk(aReg0.x, aReg0.y); w0.y = cvtpk(aReg0.z, aReg0.w);
        w0.z = cvtpk(aReg1.x, aReg1.y); w0.w = cvtpk(aReg1.z, aReg1.w);
        w1.x = cvtpk(aReg2.x, aReg2.y); w1.y = cvtpk(aReg2.z, aReg2.w);
        w1.z = cvtpk(aReg3.x, aReg3.y); w1.w = cvtpk(aReg3.z, aReg3.w);
        *(uint4*)&As[ci0 * 8] = w0;
        *(uint4*)&As[ci1 * 8] = w1;
    };
    auto STAGEB = [&](unsigned short* Bs, int kt) {
        gload_lds16(bS0 + kt * 32, Bs + (cb + 0) * 8);
        gload_lds16(bS1 + kt * 32, Bs + (cb + 256) * 8);
    };
    auto COMPUTE = [&](const unsigned short* A, const unsigned short* B) {
        bf16x8 aF[4], bF[4];
#pragma unroll
        for (int mf = 0; mf < 4; ++mf)
            aF[mf] = *(const bf16x8*)&A[(wm * 64 + mf * 16 + (lane & 15)) * 32 + (lane >> 4) * 8];
#pragma unroll
        for (int nf = 0; nf < 4; ++nf)
            bF[nf] = *(const bf16x8*)&B[(wn * 64 + nf * 16 + (lane & 15)) * 32 + (lane >> 4) * 8];
#pragma unroll
        for (int mf = 0; mf < 4; ++mf)
#pragma unroll
            for (int nf = 0; nf < 4; ++nf)
                acc[mf][nf] = __builtin_amdgcn_mfma_f32_16x16x32_bf16(aF[mf], bF[nf], acc[mf][nf], 0, 0, 0);
    };

    // prologue: stage tile 0
    LOADA(0);
    STAGEB(Bs0, 0);
    WRITEA(As0);
    __syncthreads();

    for (int t = 0; t < 12; ++t) {
        unsigned short* Acur = (t & 1) ? As1 : As0;
        unsigned short* Bcur = (t & 1) ? Bs1 : Bs0;
        unsigned short* Anx  = (t & 1) ? As0 : As1;
        unsigned short* Bnx  = (t & 1) ? Bs0 : Bs1;
        if (t < 11) {
            LOADA(t + 1);        // issue f32 loads early; latency hides under COMPUTE
            STAGEB(Bnx, t + 1);  // async global->LDS for B
        }
        COMPUTE(Acur, Bcur);
        if (t < 11) WRITEA(Anx); // cvt + ds_write after compute
        __syncthreads();         // drains vmcnt+lgkmcnt: B loads + A writes visible
    }

    // ---- epilogue: 2 phases (wm = 0,1), LDS tile Ct[64][136], coalesced stores ----
    unsigned short* Ct = smem;                  // [64][136] = 17408 B
    const int co = tid & 15;                    // col octet for store pass
    const int rr = tid >> 4;                    // row within 16-row group
    const int colg = col0 + co * 8;
    const int p = colg / 384;
    const int rem = colg - p * 384;
    const int h = rem >> 6;
    const int d = rem & 63;
    unsigned short* dst = (p == 0) ? qO : ((p == 1) ? kO : vO);

#pragma unroll
    for (int ph = 0; ph < 2; ++ph) {
        if (wm == ph) {
#pragma unroll
            for (int mf = 0; mf < 4; ++mf)
#pragma unroll
                for (int nf = 0; nf < 4; ++nf)
#pragma unroll
                    for (int r = 0; r < 4; ++r)
                        Ct[(mf * 16 + (lane >> 4) * 4 + r) * 136 + wn * 64 + nf * 16 + (lane & 15)] =
                            f2b(acc[mf][nf][r]);
        }
        __syncthreads();
#pragma unroll
        for (int it = 0; it < 4; ++it) {
            const int r_loc = it * 16 + rr;
            const int m = row0 + ph * 64 + r_loc;
            const int b = m >> 8, t = m & 255;
            uint4 val = *(const uint4*)&Ct[r_loc * 136 + co * 8];
            *(uint4*)&dst[(size_t)((b * 6 + h) * 256 + t) * 64 + d] = val;
        }
        __syncthreads();
    }
}

// ---------------- attention ----------------
// block = one (b,h); 512 threads = 8 waves; wave w owns q rows [w*32, w*32+32)
// S^T = K * Q^T via mfma_32x32x16 -> lane owns one q col; V transposed into LDS.
// defer-max: skip O-rescale when pmax <= m+8 (P bounded by e^8, safe in f32 accum).
// Ot (epilogue tile) ALIASES Ks — requires the __syncthreads before Ot writes.

__global__ __launch_bounds__(512, 4) void attn_kernel(
    const unsigned short* __restrict__ Qg,   // [B][H][T][D]
    const unsigned short* __restrict__ Kg,   // [B][H][T][D]
    const unsigned short* __restrict__ Vg,   // [B][H][T][D]
    unsigned short* __restrict__ Og)         // [B*T][384], col h*64+d
{
    extern __shared__ __align__(16) unsigned short asmem[];
    unsigned short* Ks = asmem;                 // 256*72 = 18432 elems
    unsigned short* Vs = asmem + 256 * 72;      // 64*264 = 16896 elems
    unsigned short* Ot = asmem;                 // aliases Ks (8*32*72 = 18432 elems)
    const int bh = blockIdx.x;
    const int b = bh / 6, h = bh - b * 6;
    const int tid = threadIdx.x;
    const int lane = tid & 63;
    const int w = tid >> 6;
    const int lo = lane & 31, hi = lane >> 5;

    const unsigned short* kg = Kg + (size_t)bh * 256 * 64;
#pragma unroll
    for (int j = 0; j < 4; ++j) {
        int chunk = tid + 512 * j;               // 2048 chunks of 8 elems
        int key = chunk >> 3, dc = (chunk & 7) * 8;
        *(uint4*)&Ks[key * 72 + dc] = *(const uint4*)&kg[key * 64 + dc];
    }
    // stage V transposed: unit u -> t-pair t2, d-octet dm.  Vs[d][t] = V[t][d]
    {
        const unsigned short* vg = Vg + (size_t)bh * 256 * 64;
        uint32_t* Vs32 = (uint32_t*)Vs;
#pragma unroll
        for (int i = 0; i < 2; ++i) {
            int u = tid + 512 * i;                       // 10-bit unit id
            int t2 = (u & 31) | ((u >> 8) << 5);         // 0..127
            int dm = (u >> 5) & 7;                       // d-octet
            uint4 r0 = *(const uint4*)&vg[(2 * t2 + 0) * 64 + dm * 8];
            uint4 r1 = *(const uint4*)&vg[(2 * t2 + 1) * 64 + dm * 8];
            const unsigned short* e0 = (const unsigned short*)&r0;
            const unsigned short* e1 = (const unsigned short*)&r1;
#pragma unroll
            for (int j = 0; j < 8; ++j)
                Vs32[(dm * 8 + j) * 132 + t2] = (uint32_t)e0[j] | ((uint32_t)e1[j] << 16);
        }
    }
    __syncthreads();

    const int q0 = w * 32;
    const unsigned short* qg = Qg + (size_t)bh * 256 * 64 + (size_t)(q0 + lo) * 64 + hi * 8;
    bf16x8 qF[4];
#pragma unroll
    for (int dc = 0; dc < 4; ++dc) qF[dc] = *(const bf16x8*)(qg + dc * 16);

    float m = -1e30f, ssum = 0.f;
    f32x16 o0, o1;
#pragma unroll
    for (int r = 0; r < 16; ++r) { o0[r] = 0.f; o1[r] = 0.f; }

    for (int kt = 0; kt <= w; ++kt) {
        f32x16 s;
#pragma unroll
        for (int r = 0; r < 16; ++r) s[r] = 0.f;
        __builtin_amdgcn_s_setprio(1);
#pragma unroll
        for (int dc = 0; dc < 4; ++dc) {
            bf16x8 aK = *(const bf16x8*)&Ks[(kt * 32 + lo) * 72 + dc * 16 + hi * 8];
            s = __builtin_amdgcn_mfma_f32_32x32x16_bf16(aK, qF[dc], s, 0, 0, 0);
        }
        __builtin_amdgcn_s_setprio(0);
        float p[16];
        float pmax = -1e30f;
        const bool diag = (kt == w);
#pragma unroll
        for (int r = 0; r < 16; ++r) {
            float sv = s[r] * 0.125f;
            const int keyl = (r & 3) + 8 * (r >> 2) + 4 * hi;
            if (diag && keyl > lo) sv = -1e30f;
            p[r] = sv;
            pmax = fmaxf(pmax, sv);
        }
        pmax = fmaxf(pmax, __shfl_xor(pmax, 32, 64));
        // defer-max (T13): only rescale when the new tile max exceeds m by > 8.
        if (pmax > m + 8.f) {
            const float sf = __expf(m - pmax);
            m = pmax;
            ssum *= sf;
#pragma unroll
            for (int r = 0; r < 16; ++r) { o0[r] *= sf; o1[r] *= sf; }
        }
        float rs = 0.f;
#pragma unroll
        for (int r = 0; r < 16; ++r) { p[r] = __expf(p[r] - m); rs += p[r]; }
        rs += __shfl_xor(rs, 32, 64);
        ssum += rs;

        // redistribute P to PV B-operand layout: lane needs P^T[key=(kc*16 + hi*8 + i)][q=lo]
        union { unsigned short u[16]; bf16x8 v[2]; } P;
        {
            float recv[4];
#pragma unroll
            for (int j2 = 0; j2 < 4; ++j2) {
                float sendv = hi ? p[j2] : p[4 + j2];
                recv[j2] = __shfl_xor(sendv, 32, 64);
            }
#pragma unroll
            for (int i = 0; i < 4; ++i) P.u[i]     = f2b(hi ? recv[i] : p[i]);
#pragma unroll
            for (int i = 0; i < 4; ++i) P.u[4 + i] = f2b(hi ? p[4 + i] : recv[i]);
        }
        {
            float recv[4];
#pragma unroll
            for (int j2 = 0; j2 < 4; ++j2) {
                float sendv = hi ? p[8 + j2] : p[12 + j2];
                recv[j2] = __shfl_xor(sendv, 32, 64);
            }
#pragma unroll
            for (int i = 0; i < 4; ++i) P.u[8 + i]  = f2b(hi ? recv[i] : p[8 + i]);
#pragma unroll
            for (int i = 0; i < 4; ++i) P.u[12 + i] = f2b(hi ? p[12 + i] : recv[i]);
        }

        __builtin_amdgcn_s_setprio(1);
#pragma unroll
        for (int kc = 0; kc < 2; ++kc) {
            bf16x8 aV0 = *(const bf16x8*)&Vs[lo * 264 + kt * 32 + kc * 16 + hi * 8];
            o0 = __builtin_amdgcn_mfma_f32_32x32x16_bf16(aV0, P.v[kc], o0, 0, 0, 0);
            bf16x8 aV1 = *(const bf16x8*)&Vs[(32 + lo) * 264 + kt * 32 + kc * 16 + hi * 8];
            o1 = __builtin_amdgcn_mfma_f32_32x32x16_bf16(aV1, P.v[kc], o1, 0, 0, 0);
        }
        __builtin_amdgcn_s_setprio(0);
    }

    // ---- epilogue: per-wave LDS transpose (Ot aliases Ks!), then coalesced stores ----
    __syncthreads();   // ALL waves must finish reading Ks before Ot overwrites it
    const float inv = 1.f / ssum;
    {
        uint32_t* ot32 = (uint32_t*)&Ot[w * 32 * 72];
#pragma unroll
        for (int g = 0; g < 4; ++g) {
            const int dbase0 = 8 * g + 4 * hi;
            uint32_t w0 = pk2(o0[4 * g + 0] * inv, o0[4 * g + 1] * inv);
            uint32_t w1 = pk2(o0[4 * g + 2] * inv, o0[4 * g + 3] * inv);
            int dw = lo * 36 + (dbase0 >> 1);
            ot32[dw] = w0;
            ot32[dw + 1] = w1;
            uint32_t w2 = pk2(o1[4 * g + 0] * inv, o1[4 * g + 1] * inv);
            uint32_t w3 = pk2(o1[4 * g + 2] * inv, o1[4 * g + 3] * inv);
            int dw1 = lo * 36 + ((32 + dbase0) >> 1);
            ot32[dw1] = w2;
            ot32[dw1 + 1] = w3;
        }
    }
    __syncthreads();
    {
        const unsigned short* ot = &Ot[w * 32 * 72];
        const int q = lane >> 1;                        // 0..31
        const int half = (lane & 1) * 32;               // elem offset 0 / 32
        unsigned short* og = Og + (size_t)(b * 256 + q0 + q) * 384 + h * 64 + half;
#pragma unroll
        for (int jj = 0; jj < 4; ++jj) {
            uint4 val = *(const uint4*)&ot[q * 72 + half + jj * 8];
            *(uint4*)&og[jj * 8] = val;
        }
    }
}

// ---------------- GEMM2: output projection ----------------
// 128x128 tile, BK=32, 3-buffer counted-vmcnt pipeline (pinned), XCD-swizzled (nwg=768),
// T2 XOR-swizzled LDS.

__global__ __launch_bounds__(256, 3) void gemm_proj(
    const unsigned short* __restrict__ ob,   // [32768][384]
    const unsigned short* __restrict__ wpt,  // [384][384] (pre-transposed)
    const float* __restrict__ bp,            // [384]
    float* __restrict__ out)                 // [32768][384]
{
    __shared__ __align__(16) unsigned short As[3][128 * 32];
    __shared__ __align__(16) unsigned short Bs[3][128 * 32];
    const int tid  = threadIdx.x;
    const int lane = tid & 63;
    const int w    = tid >> 6;
    const int wm = w >> 1, wn = w & 1;

    const int flat = blockIdx.y * 3 + blockIdx.x;
    const int swz = (flat & 7) * 96 + (flat >> 3);
    const int bx = swz % 3, by = swz / 3;
    const int col0 = bx * 128;
    const int row0 = by * 128;

    const unsigned short* Abase = ob  + (size_t)row0 * 384;
    const unsigned short* Bbase = wpt + (size_t)col0 * 384;

    f32x4 acc[4][4];
#pragma unroll
    for (int mf = 0; mf < 4; ++mf)
#pragma unroll
        for (int nf = 0; nf < 4; ++nf)
#pragma unroll
            for (int r = 0; r < 4; ++r) acc[mf][nf][r] = 0.f;

    const int ci0 = tid;
    const int ci1 = tid + 256;
    const int r0c = ci0 >> 2, o0c = (ci0 & 3) ^ ((ci0 >> 3) & 3);
    const int r1c = ci1 >> 2, o1c = (ci1 & 3) ^ ((ci1 >> 3) & 3);
    const unsigned short* aSrc0 = Abase + (size_t)r0c * 384 + o0c * 8;
    const unsigned short* aSrc1 = Abase + (size_t)r1c * 384 + o1c * 8;
    const unsigned short* bSrc0 = Bbase + (size_t)r0c * 384 + o0c * 8;
    const unsigned short* bSrc1 = Bbase + (size_t)r1c * 384 + o1c * 8;
    const int cb = w * 64;

    auto STAGE = [&](int buf, int kt) {
        const int k0_ = kt * 32;
        gload_lds16(aSrc0 + k0_, (unsigned short*)As[buf] + (cb + 0) * 8);
        gload_lds16(bSrc0 + k0_, (unsigned short*)Bs[buf] + (cb + 0) * 8);
        gload_lds16(aSrc1 + k0_, (unsigned short*)As[buf] + (cb + 256) * 8);
        gload_lds16(bSrc1 + k0_, (unsigned short*)Bs[buf] + (cb + 256) * 8);
    };

    const int fr = lane & 15;
    const int oc = (lane >> 4) ^ ((fr >> 1) & 3);

    auto COMPUTE = [&](int buf) {
        const unsigned short* A = As[buf];
        const unsigned short* B = Bs[buf];
        bf16x8 aF[4], bF[4];
#pragma unroll
        for (int mf = 0; mf < 4; ++mf)
            aF[mf] = *(const bf16x8*)&A[(wm * 64 + mf * 16 + fr) * 32 + oc * 8];
#pragma unroll
        for (int nf = 0; nf < 4; ++nf)
            bF[nf] = *(const bf16x8*)&B[(wn * 64 + nf * 16 + fr) * 32 + oc * 8];
#pragma unroll
        for (int mf = 0; mf < 4; ++mf)
#pragma unroll
            for (int nf = 0; nf < 4; ++nf)
                acc[mf][nf] = __builtin_amdgcn_mfma_f32_16x16x32_bf16(aF[mf], bF[nf], acc[mf][nf], 0, 0, 0);
    };

    STAGE(0, 0);
    STAGE(1, 1);
    SBAR0();
    int bufS = 2, bufC = 0;
    for (int t = 0; t < 10; ++t) {
        STAGE(bufS, t + 2);
        bufS = (bufS == 2) ? 0 : bufS + 1;
        SBAR0();
        asm volatile("s_waitcnt vmcnt(8)" ::: "memory");
        SBAR0();
        __builtin_amdgcn_s_barrier();
        SBAR0();
        COMPUTE(bufC);
        bufC = (bufC == 2) ? 0 : bufC + 1;
        SBAR0();
        __builtin_amdgcn_s_barrier();
        SBAR0();
    }
    asm volatile("s_waitcnt vmcnt(4)" ::: "memory");
    SBAR0();
    __builtin_amdgcn_s_barrier();
    SBAR0();
    COMPUTE(1);
    SBAR0();
    __builtin_amdgcn_s_barrier();
    SBAR0();
    asm volatile("s_waitcnt vmcnt(0)" ::: "memory");
    SBAR0();
    __builtin_amdgcn_s_barrier();
    SBAR0();
    COMPUTE(2);

#pragma unroll
    for (int nf = 0; nf < 4; ++nf) {
        const int col = col0 + wn * 64 + nf * 16 + (lane & 15);
        const float bias = bp[col];
#pragma unroll
        for (int mf = 0; mf < 4; ++mf) {
            const int mbase = row0 + wm * 64 + mf * 16 + ((lane >> 4) * 4);
#pragma unroll
            for (int r = 0; r < 4; ++r) {
                const int mrow = mbase + r;
                out[(size_t)mrow * 384 + col] = acc[mf][nf][r] + bias;
            }
        }
    }
}

// ---------------- launch ----------------

extern "C" void kernel_launch(void* const* d_in, const int* in_sizes, int n_in,
                              void* d_out, int out_size, void* d_ws, size_t ws_size,
                              hipStream_t stream) {
    const float* x  = (const float*)d_in[0];
    const float* Wq = (const float*)d_in[1];
    const float* Wk = (const float*)d_in[2];
    const float* Wv = (const float*)d_in[3];
    const float* Wp = (const float*)d_in[4];
    const float* bp = (const float*)d_in[5];
    float* out = (float*)d_out;

    char* ws = (char*)d_ws;
    unsigned short* ob  = (unsigned short*)(ws);              // 25165824 B (attn output O)
    unsigned short* qb  = (unsigned short*)(ws + 25165824);   // 25165824 B
    unsigned short* kb  = (unsigned short*)(ws + 50331648);   // 25165824 B
    unsigned short* vb  = (unsigned short*)(ws + 75497472);   // 25165824 B
    unsigned short* wt  = (unsigned short*)(ws + 100663296);  // 884736 B (1152x384)
    unsigned short* wpt = (unsigned short*)(ws + 101548032);  // 294912 B (384x384)

    cvt_w_kernel<<<2304, 256, 0, stream>>>(Wq, Wk, Wv, Wp, wt, wpt);
    gemm_qkv<<<dim3(9, 256), 256, 32768, stream>>>(x, wt, qb, kb, vb);
    attn_kernel<<<768, 512, 70656, stream>>>(qb, kb, vb, ob);
    gemm_proj<<<dim3(3, 256), 256, 0, stream>>>(ob, wpt, bp, out);
}